// Round 6
// baseline (1584.040 us; speedup 1.0000x reference)
//
#include <hip/hip_runtime.h>
#include <hip/hip_bf16.h>

// Fused Comm_OUT pipeline, batch-row-parallel (GRU recurrence is per-row).
// Round-6: weights read DIRECTLY from d_in (round-2 evidence: d_in weight
// reads are ~100% L2/L3-absorbed, FETCH ~= hw input only; packed scratch
// buffers leaked ~0.9 GB beyond-L2 traffic). Out is staged in LDS (bf16)
// and flushed every 4 steps as full aligned 128B lines (kills the 6x WRITE
// amplification + RFO from 64B scattered stores).
// 256 blocks x 1024 threads (16 waves = rg(2) x cg(8)), BM=32 rows, 1/CU.
// Runtime dtype detection (inputs fp32 or bf16) via g_flag.

typedef __attribute__((ext_vector_type(8))) short bf16x8;   // 8 x bf16 (4 VGPRs)
typedef __attribute__((ext_vector_type(4))) float f32x4;    // MFMA accumulator
typedef __attribute__((ext_vector_type(4))) unsigned short u16x4;

#define MFMA16(a, b, c) __builtin_amdgcn_mfma_f32_16x16x32_bf16((a), (b), (c), 0, 0, 0)

constexpr int F   = 640;
constexpr int H   = 256;
constexpr int LSTEPS = 20;
constexpr int CO  = 32;
constexpr int LDP = 264;   // padded bf16 row stride for h/y/z tiles
constexpr int OBW = 132;   // out-stage row stride (ushort): 128 cols + 4 pad

__device__ int g_flag;     // 1 = inputs are fp32

__device__ __forceinline__ float bf2f(__hip_bfloat16 x) { return __bfloat162float(x); }
__device__ __forceinline__ unsigned short f2bs(float f) {
    __hip_bfloat16 h = __float2bfloat16(f);
    return *reinterpret_cast<unsigned short*>(&h);
}
__device__ __forceinline__ float bs2f(unsigned short s) {
    unsigned int u = ((unsigned int)s) << 16;
    return *reinterpret_cast<float*>(&u);
}
__device__ __forceinline__ bf16x8 lds8(const unsigned short* p) {
    return *reinterpret_cast<const bf16x8*>(p);
}
__device__ __forceinline__ float sigm(float x) {
    return 1.0f / (1.0f + __expf(-x));
}

// load 8 contiguous elements as a bf16 MFMA fragment (dtype-templated)
template<bool F32>
__device__ __forceinline__ bf16x8 g8(const void* base, size_t off) {
    if constexpr (!F32) {
        return *reinterpret_cast<const bf16x8*>((const __hip_bfloat16*)base + off);
    } else {
        const float* f = (const float*)base + off;
        float4 lo = *reinterpret_cast<const float4*>(f);
        float4 hi = *reinterpret_cast<const float4*>(f + 4);
        bf16x8 r;
        r[0] = (short)f2bs(lo.x); r[1] = (short)f2bs(lo.y);
        r[2] = (short)f2bs(lo.z); r[3] = (short)f2bs(lo.w);
        r[4] = (short)f2bs(hi.x); r[5] = (short)f2bs(hi.y);
        r[6] = (short)f2bs(hi.z); r[7] = (short)f2bs(hi.w);
        return r;
    }
}

template<bool F32>
__device__ __forceinline__ float ld1(const void* base, int i) {
    if constexpr (!F32) return bf2f(((const __hip_bfloat16*)base)[i]);
    else                return ((const float*)base)[i];
}

// ---------------- dtype detect: v1 (uniform[0.5,1.5]) ----------------
__global__ void detect_dtype(const void* v1) {
    const unsigned short* u = (const unsigned short*)v1;
    int f32 = 0;
    for (int i = 0; i < 8; ++i) {
        unsigned short s = u[i];
        __hip_bfloat16 h = *reinterpret_cast<__hip_bfloat16*>(&s);
        float v = __bfloat162float(h);
        if (!(v >= 0.25f && v <= 2.0f)) f32 = 1;
    }
    g_flag = f32;
}

// ---------------- main fused kernel ----------------
template<bool F32>
__device__ __forceinline__ void fast_pipe(
    const void* hw,
    const void* Wlin, const void* blin,
    const void* g1, const void* be1, const void* m1, const void* v1, const void* a1,
    const void* Wih, const void* Whh, const void* bih, const void* bhh,
    const void* g2, const void* be2, const void* m2, const void* v2, const void* a2,
    const void* Wc,  const void* bc,
    const void* g3, const void* be3, const void* m3, const void* v3, const void* a3,
    const void* Wmu, const void* bmu,
    void* out,
    unsigned short* hb, unsigned short* yb, unsigned short* zb, unsigned short* ob)
{
    const int tid  = threadIdx.x;
    const int w    = tid >> 6;        // wave 0..15
    const int cg   = w & 7;           // column group (32 cols)
    const int rg   = w >> 3;          // row group (16 rows)
    const int lane = tid & 63;
    const int m16  = lane & 15;
    const int q    = lane >> 4;
    const int row0 = blockIdx.x * 32;
    const int c0 = cg * 32 + m16;
    const int c1 = c0 + 16;
    const int cc2[2] = { c0, c1 };

    // persistent per-step params (folded)
    float s2v[2], t2v[2], s3v[2], t3f[2], bhhn[2];
    #pragma unroll
    for (int j = 0; j < 2; ++j) {
        const int cc = cc2[j];
        float s;
        s = ld1<F32>(g2, cc) * rsqrtf(ld1<F32>(v2, cc) + 1e-5f);
        s2v[j] = s; t2v[j] = ld1<F32>(be2, cc) - ld1<F32>(m2, cc) * s;
        s = ld1<F32>(g3, cc) * rsqrtf(ld1<F32>(v3, cc) + 1e-5f);
        s3v[j] = s;
        t3f[j] = (ld1<F32>(bc, cc) - ld1<F32>(m3, cc)) * s + ld1<F32>(be3, cc);
        bhhn[j] = ld1<F32>(bhh, 2 * H + cc);
    }
    const float a2v = ld1<F32>(a2, 0), a3v = ld1<F32>(a3, 0);

    // ---- Phase 1: x = prelu(bn1(rows @ Wlin^T + blin)) -> yb ----
    {
        f32x4 xacc[2] = {};
        #pragma unroll 5
        for (int kk = 0; kk < F / 32; ++kk) {
            bf16x8 a  = g8<F32>(hw, (size_t)(row0 + rg * 16 + m16) * F + kk * 32 + q * 8);
            bf16x8 b0 = g8<F32>(Wlin, (size_t)c0 * F + kk * 32 + q * 8);
            bf16x8 b1 = g8<F32>(Wlin, (size_t)c1 * F + kk * 32 + q * 8);
            xacc[0] = MFMA16(a, b0, xacc[0]);
            xacc[1] = MFMA16(a, b1, xacc[1]);
        }
        #pragma unroll
        for (int j = 0; j < 2; ++j) {
            const int cc = cc2[j];
            float s = ld1<F32>(g1, cc) * rsqrtf(ld1<F32>(v1, cc) + 1e-5f);
            float t = ld1<F32>(be1, cc) - ld1<F32>(m1, cc) * s;
            float bl = ld1<F32>(blin, cc);
            float av = ld1<F32>(a1, 0);
            #pragma unroll
            for (int r = 0; r < 4; ++r) {
                float vv = (xacc[j][r] + bl) * s + t;
                vv = (vv >= 0.0f) ? vv : av * vv;
                yb[(rg * 16 + q * 4 + r) * LDP + cc] = f2bs(vv);
            }
        }
    }
    __syncthreads();   // x visible in yb

    // ---- Phase 2: gi = x @ Wih^T + (bih + bhh[r,z])  (registers) ----
    f32x4 gi[3][2] = {};
    {
        const unsigned short* xa = yb + (rg * 16 + m16) * LDP + q * 8;
        #pragma unroll
        for (int g = 0; g < 3; ++g)
            #pragma unroll
            for (int kk = 0; kk < 8; ++kk) {
                bf16x8 a  = lds8(xa + kk * 32);
                bf16x8 b0 = g8<F32>(Wih, (size_t)(g * H + c0) * H + kk * 32 + q * 8);
                bf16x8 b1 = g8<F32>(Wih, (size_t)(g * H + c1) * H + kk * 32 + q * 8);
                gi[g][0] = MFMA16(a, b0, gi[g][0]);
                gi[g][1] = MFMA16(a, b1, gi[g][1]);
            }
        #pragma unroll
        for (int g = 0; g < 3; ++g)
            #pragma unroll
            for (int j = 0; j < 2; ++j) {
                float bias = ld1<F32>(bih, g * H + cc2[j]);
                if (g < 2) bias += ld1<F32>(bhh, g * H + cc2[j]);
                #pragma unroll
                for (int r = 0; r < 4; ++r) gi[g][j][r] += bias;
            }
    }

    // ---- GRU loop + fused downstream ----
    // Per step t: [gh reads hb(t-1)] [gates] A [write hb,yb] B1
    //             [Wc reads yb -> zb] B2 [Wmu reads zb -> ob]
    //             (t%4==3): C [flush ob -> out, full 128B lines]
    float hreg[2][4] = {};
    const unsigned short* haP = hb + (rg * 16 + m16) * LDP + q * 8;
    const unsigned short* yaP = yb + (rg * 16 + m16) * LDP + q * 8;
    const int mto = (w >> 1) & 1;
    const int nto = w & 1;
    const unsigned short* zaP = zb + (mto * 16 + m16) * LDP + q * 8;
    const float bmuv = (w < 4) ? ld1<F32>(bmu, nto * 16 + m16) : 0.0f;

    #pragma unroll 1
    for (int t = 0; t < LSTEPS; ++t) {
        f32x4 gh[3][2] = {};
        if (t > 0) {
            #pragma unroll
            for (int g = 0; g < 3; ++g)
                #pragma unroll
                for (int kk = 0; kk < 8; ++kk) {
                    bf16x8 a  = lds8(haP + kk * 32);
                    bf16x8 b0 = g8<F32>(Whh, (size_t)(g * H + c0) * H + kk * 32 + q * 8);
                    bf16x8 b1 = g8<F32>(Whh, (size_t)(g * H + c1) * H + kk * 32 + q * 8);
                    gh[g][0] = MFMA16(a, b0, gh[g][0]);
                    gh[g][1] = MFMA16(a, b1, gh[g][1]);
                }
        }
        // gates + h update + y = prelu(bn2(h))
        float yv[2][4];
        #pragma unroll
        for (int j = 0; j < 2; ++j)
            #pragma unroll
            for (int r = 0; r < 4; ++r) {
                float rr = sigm(gi[0][j][r] + gh[0][j][r]);
                float zz = sigm(gi[1][j][r] + gh[1][j][r]);
                float nin = gi[2][j][r] + rr * (gh[2][j][r] + bhhn[j]);
                float nn = 2.0f * sigm(2.0f * nin) - 1.0f;   // tanh
                float hh = (1.0f - zz) * nn + zz * hreg[j][r];
                hreg[j][r] = hh;
                float y = hh * s2v[j] + t2v[j];
                yv[j][r] = (y >= 0.0f) ? y : a2v * y;
            }
        __syncthreads();   // A
        #pragma unroll
        for (int j = 0; j < 2; ++j)
            #pragma unroll
            for (int r = 0; r < 4; ++r) {
                const int idx = (rg * 16 + q * 4 + r) * LDP + cc2[j];
                hb[idx] = f2bs(hreg[j][r]);
                yb[idx] = f2bs(yv[j][r]);
            }
        __syncthreads();   // B1: h/y visible

        // w2 = y @ Wc^T -> z -> zb
        f32x4 w2[2] = {};
        #pragma unroll
        for (int kk = 0; kk < 8; ++kk) {
            bf16x8 a  = lds8(yaP + kk * 32);
            bf16x8 b0 = g8<F32>(Wc, (size_t)c0 * H + kk * 32 + q * 8);
            bf16x8 b1 = g8<F32>(Wc, (size_t)c1 * H + kk * 32 + q * 8);
            w2[0] = MFMA16(a, b0, w2[0]);
            w2[1] = MFMA16(a, b1, w2[1]);
        }
        #pragma unroll
        for (int j = 0; j < 2; ++j)
            #pragma unroll
            for (int r = 0; r < 4; ++r) {
                float z0 = w2[j][r] * s3v[j] + t3f[j];
                z0 = (z0 >= 0.0f) ? z0 : a3v * z0;
                zb[(rg * 16 + q * 4 + r) * LDP + cc2[j]] = f2bs(z0);
            }
        __syncthreads();   // B2: z visible

        // out_t = z @ Wmu^T + bmu -> ob (LDS stage; waves 0..3)
        if (w < 4) {
            f32x4 o = {};
            #pragma unroll
            for (int kk = 0; kk < 8; ++kk) {
                bf16x8 a = lds8(zaP + kk * 32);
                bf16x8 b = g8<F32>(Wmu, (size_t)(nto * 16 + m16) * H + kk * 32 + q * 8);
                o = MFMA16(a, b, o);
            }
            #pragma unroll
            for (int r = 0; r < 4; ++r) {
                float vv = o[r] + bmuv;
                ob[(mto * 16 + q * 4 + r) * OBW + (t & 3) * CO + nto * 16 + m16] = f2bs(vv);
            }
        }

        // flush every 4 steps: full, aligned, coalesced lines
        if ((t & 3) == 3) {
            __syncthreads();   // C: ob chunk complete
            const int row = tid >> 5;          // 0..31
            const int l32 = tid & 31;          // 0..31
            const int tb  = t - 3;
            u16x4 v4 = *reinterpret_cast<const u16x4*>(ob + row * OBW + l32 * 4);
            const size_t oidx = (size_t)(row0 + row) * (LSTEPS * CO) + tb * CO + l32 * 4;
            if constexpr (F32) {
                float4 f4 = { bs2f(v4.x), bs2f(v4.y), bs2f(v4.z), bs2f(v4.w) };
                *reinterpret_cast<float4*>((float*)out + oidx) = f4;
            } else {
                *reinterpret_cast<u16x4*>((__hip_bfloat16*)out + oidx) = v4;
            }
            // no barrier needed after flush: next write to this ob slot happens
            // only after B2(t+1), which all waves (incl. flushers) must reach.
        }
    }
}

__global__ __launch_bounds__(1024, 4) void comm_fast(
    const void* hw,
    const void* Wlin, const void* blin,
    const void* g1, const void* be1, const void* m1, const void* v1, const void* a1,
    const void* Wih, const void* Whh, const void* bih, const void* bhh,
    const void* g2, const void* be2, const void* m2, const void* v2, const void* a2,
    const void* Wc,  const void* bc,
    const void* g3, const void* be3, const void* m3, const void* v3, const void* a3,
    const void* Wmu, const void* bmu,
    void* out)
{
    __shared__ __align__(16) unsigned short hb[32 * LDP];
    __shared__ __align__(16) unsigned short yb[32 * LDP];
    __shared__ __align__(16) unsigned short zb[32 * LDP];
    __shared__ __align__(16) unsigned short ob[32 * OBW];
    if (g_flag) {
        fast_pipe<true >(hw, Wlin, blin, g1, be1, m1, v1, a1, Wih, Whh, bih, bhh,
                         g2, be2, m2, v2, a2, Wc, bc, g3, be3, m3, v3, a3, Wmu, bmu,
                         out, hb, yb, zb, ob);
    } else {
        fast_pipe<false>(hw, Wlin, blin, g1, be1, m1, v1, a1, Wih, Whh, bih, bhh,
                         g2, be2, m2, v2, a2, Wc, bc, g3, be3, m3, v3, a3, Wmu, bmu,
                         out, hb, yb, zb, ob);
    }
}

extern "C" void kernel_launch(void* const* d_in, const int* in_sizes, int n_in,
                              void* d_out, int out_size, void* d_ws, size_t ws_size,
                              hipStream_t stream) {
    (void)in_sizes; (void)n_in; (void)out_size; (void)d_ws; (void)ws_size;
    detect_dtype<<<dim3(1), dim3(1), 0, stream>>>(d_in[6]);
    comm_fast<<<dim3(256), dim3(1024), 0, stream>>>(
        d_in[0],
        d_in[1], d_in[2],
        d_in[3], d_in[4], d_in[5], d_in[6], d_in[7],
        d_in[8], d_in[9], d_in[10], d_in[11],
        d_in[12], d_in[13], d_in[14], d_in[15], d_in[16],
        d_in[17], d_in[18],
        d_in[19], d_in[20], d_in[21], d_in[22], d_in[23],
        d_in[24], d_in[25],
        d_out);
}

// Round 7
// 615.612 us; speedup vs baseline: 2.5731x; 2.5731x over previous
//
#include <hip/hip_runtime.h>
#include <hip/hip_bf16.h>

// Fused Comm_OUT pipeline, batch-row-parallel (GRU recurrence is per-row).
// Round-7: packed bf16 weight fragment-streams (g_wpk, coalesced 16B/lane)
// + 2 m-tiles per wave (each loaded B-fragment feeds 2 MFMAs) — halves the
// weight-load instruction stream vs r3-r5 at equal coalescing. Evidence:
// dur tracks weight-load transaction count across r2..r6 (~0.09us/k-tx),
// not FETCH bytes / MFMA / VALU.
// 256 blocks x 512 threads (8 waves, wave w = column-group cg), BM=32, 1/CU.
// Runtime dtype detection (inputs fp32 or bf16) via g_flag.

typedef __attribute__((ext_vector_type(8))) short bf16x8;   // 8 x bf16 (4 VGPRs)
typedef __attribute__((ext_vector_type(4))) float f32x4;    // MFMA accumulator

#define MFMA16(a, b, c) __builtin_amdgcn_mfma_f32_16x16x32_bf16((a), (b), (c), 0, 0, 0)

constexpr int F   = 640;
constexpr int H   = 256;
constexpr int LSTEPS = 20;
constexpr int CO  = 32;
constexpr int LDP = 264;   // padded bf16 row stride (16B-aligned rows)

// packed-weight element offsets inside g_wpk
constexpr size_t WHH_E  = 0;                    // 8cg*3g*8kk*2j*64lane*8 = 196608
constexpr size_t WIH_E  = 196608;               // 196608
constexpr size_t WC_E   = 393216;               // 8cg*8kk*2j*64*8       = 65536
constexpr size_t WMU_E  = 458752;               // 2w*8kk*64*8           = 8192
constexpr size_t WLIN_E = 466944;               // 8cg*20kk*2j*64*8      = 163840
constexpr size_t PK_ELEMS = 630784;

__device__ __align__(16) unsigned short g_wpk[PK_ELEMS];
__device__ int g_flag;     // 1 = inputs are fp32

__device__ __forceinline__ float bf2f(__hip_bfloat16 x) { return __bfloat162float(x); }
__device__ __forceinline__ unsigned short f2bs(float f) {
    __hip_bfloat16 h = __float2bfloat16(f);
    return *reinterpret_cast<unsigned short*>(&h);
}
__device__ __forceinline__ bf16x8 lds8(const unsigned short* p) {
    return *reinterpret_cast<const bf16x8*>(p);
}
__device__ __forceinline__ bf16x8 pk8(size_t eoff) {
    return *reinterpret_cast<const bf16x8*>(g_wpk + eoff);
}
__device__ __forceinline__ float sigm(float x) {
    return 1.0f / (1.0f + __expf(-x));
}

template<bool F32>
__device__ __forceinline__ bf16x8 g8(const void* base, size_t off) {
    if constexpr (!F32) {
        return *reinterpret_cast<const bf16x8*>((const __hip_bfloat16*)base + off);
    } else {
        const float* f = (const float*)base + off;
        float4 lo = *reinterpret_cast<const float4*>(f);
        float4 hi = *reinterpret_cast<const float4*>(f + 4);
        bf16x8 r;
        r[0] = (short)f2bs(lo.x); r[1] = (short)f2bs(lo.y);
        r[2] = (short)f2bs(lo.z); r[3] = (short)f2bs(lo.w);
        r[4] = (short)f2bs(hi.x); r[5] = (short)f2bs(hi.y);
        r[6] = (short)f2bs(hi.z); r[7] = (short)f2bs(hi.w);
        return r;
    }
}

template<bool F32>
__device__ __forceinline__ float ld1(const void* base, int i) {
    if constexpr (!F32) return bf2f(((const __hip_bfloat16*)base)[i]);
    else                return ((const float*)base)[i];
}

// ---------------- dtype detect: v1 (uniform[0.5,1.5]) ----------------
__global__ void detect_dtype(const void* v1) {
    const unsigned short* u = (const unsigned short*)v1;
    int f32 = 0;
    for (int i = 0; i < 8; ++i) {
        unsigned short s = u[i];
        __hip_bfloat16 h = *reinterpret_cast<__hip_bfloat16*>(&s);
        float v = __bfloat162float(h);
        if (!(v >= 0.25f && v <= 2.0f)) f32 = 1;
    }
    g_flag = f32;
}

// ---------------- weight pre-pack (fp32|bf16 -> bf16 fragment streams) ----------------
__device__ __forceinline__ unsigned short cvt1(const void* p, size_t i, bool f32) {
    if (f32) return f2bs(((const float*)p)[i]);
    return ((const unsigned short*)p)[i];
}

__global__ void prepack(const void* Wlin, const void* Wih, const void* Whh,
                        const void* Wc, const void* Wmu) {
    const bool f32 = (g_flag != 0);
    const int gid = blockIdx.x * 256 + threadIdx.x;
    const void* src;
    size_t dbase;
    int row, col0, ncols;
    if (gid < 24576) {                       // Whh [768,256]
        int idx = gid;
        int lane = idx & 63, j = (idx >> 6) & 1, kk = (idx >> 7) & 7;
        int t2 = idx >> 10, g = t2 % 3, w = t2 / 3;
        row = g * 256 + w * 32 + j * 16 + (lane & 15);
        col0 = kk * 32 + (lane >> 4) * 8;
        ncols = 256; src = Whh; dbase = WHH_E + (size_t)idx * 8;
    } else if (gid < 49152) {                // Wih [768,256]
        int idx = gid - 24576;
        int lane = idx & 63, j = (idx >> 6) & 1, kk = (idx >> 7) & 7;
        int t2 = idx >> 10, g = t2 % 3, w = t2 / 3;
        row = g * 256 + w * 32 + j * 16 + (lane & 15);
        col0 = kk * 32 + (lane >> 4) * 8;
        ncols = 256; src = Wih; dbase = WIH_E + (size_t)idx * 8;
    } else if (gid < 57344) {                // Wc [256,256]
        int idx = gid - 49152;
        int lane = idx & 63, j = (idx >> 6) & 1, kk = (idx >> 7) & 7, w = idx >> 10;
        row = w * 32 + j * 16 + (lane & 15);
        col0 = kk * 32 + (lane >> 4) * 8;
        ncols = 256; src = Wc; dbase = WC_E + (size_t)idx * 8;
    } else if (gid < 58368) {                // Wmu [32,256]
        int idx = gid - 57344;
        int lane = idx & 63, kk = (idx >> 6) & 7, w = idx >> 9;
        row = w * 16 + (lane & 15);
        col0 = kk * 32 + (lane >> 4) * 8;
        ncols = 256; src = Wmu; dbase = WMU_E + (size_t)idx * 8;
    } else if (gid < 78848) {                // Wlin [256,640]
        int idx = gid - 58368;
        int lane = idx & 63, j = (idx >> 6) & 1;
        int t1 = idx >> 7, kk = t1 % 20, w = t1 / 20;
        row = w * 32 + j * 16 + (lane & 15);
        col0 = kk * 32 + (lane >> 4) * 8;
        ncols = 640; src = Wlin; dbase = WLIN_E + (size_t)idx * 8;
    } else {
        return;
    }
    const size_t s0 = (size_t)row * ncols + col0;
    #pragma unroll
    for (int i = 0; i < 8; ++i) g_wpk[dbase + i] = cvt1(src, s0 + i, f32);
}

// ---------------- FAST PATH: BM=32, 512 threads, 8 waves, 2 m-tiles/wave ----------------
template<bool F32>
__device__ __forceinline__ void fast_pipe(
    const void* hw, const void* blin,
    const void* g1, const void* be1, const void* m1, const void* v1, const void* a1,
    const void* bih, const void* bhh,
    const void* g2, const void* be2, const void* m2, const void* v2, const void* a2,
    const void* bc,
    const void* g3, const void* be3, const void* m3, const void* v3, const void* a3,
    const void* bmu,
    void* out,
    unsigned short* hb, unsigned short* yb, unsigned short* zb)
{
    const int tid  = threadIdx.x;
    const int cg   = tid >> 6;        // wave = column group (32 cols), 0..7
    const int lane = tid & 63;
    const int m16  = lane & 15;
    const int q    = lane >> 4;
    const int row0 = blockIdx.x * 32;
    const int c0 = cg * 32 + m16;
    const int c1 = c0 + 16;
    const int cc2[2] = { c0, c1 };
    const size_t lane8 = (size_t)lane * 8;

    // persistent per-step params (folded)
    float s2v[2], t2v[2], s3v[2], t3f[2], bhhn[2];
    #pragma unroll
    for (int j = 0; j < 2; ++j) {
        const int cc = cc2[j];
        float s;
        s = ld1<F32>(g2, cc) * rsqrtf(ld1<F32>(v2, cc) + 1e-5f);
        s2v[j] = s; t2v[j] = ld1<F32>(be2, cc) - ld1<F32>(m2, cc) * s;
        s = ld1<F32>(g3, cc) * rsqrtf(ld1<F32>(v3, cc) + 1e-5f);
        s3v[j] = s;
        t3f[j] = (ld1<F32>(bc, cc) - ld1<F32>(m3, cc)) * s + ld1<F32>(be3, cc);
        bhhn[j] = ld1<F32>(bhh, 2 * H + cc);
    }
    const float a2v = ld1<F32>(a2, 0), a3v = ld1<F32>(a3, 0);

    // ---- Phase 1: x = prelu(bn1(rows @ Wlin^T + blin)) -> yb ----
    {
        f32x4 xacc[2][2] = {};   // [mt][j]
        #pragma unroll 5
        for (int kk = 0; kk < F / 32; ++kk) {
            bf16x8 a0 = g8<F32>(hw, (size_t)(row0 + m16) * F + kk * 32 + q * 8);
            bf16x8 a1 = g8<F32>(hw, (size_t)(row0 + 16 + m16) * F + kk * 32 + q * 8);
            bf16x8 b0 = pk8(WLIN_E + (size_t)((cg * 20 + kk) * 2 + 0) * 512 + lane8);
            bf16x8 b1 = pk8(WLIN_E + (size_t)((cg * 20 + kk) * 2 + 1) * 512 + lane8);
            xacc[0][0] = MFMA16(a0, b0, xacc[0][0]);
            xacc[1][0] = MFMA16(a1, b0, xacc[1][0]);
            xacc[0][1] = MFMA16(a0, b1, xacc[0][1]);
            xacc[1][1] = MFMA16(a1, b1, xacc[1][1]);
        }
        #pragma unroll
        for (int j = 0; j < 2; ++j) {
            const int cc = cc2[j];
            float s = ld1<F32>(g1, cc) * rsqrtf(ld1<F32>(v1, cc) + 1e-5f);
            float t = ld1<F32>(be1, cc) - ld1<F32>(m1, cc) * s;
            float bl = ld1<F32>(blin, cc);
            float av = ld1<F32>(a1, 0);
            #pragma unroll
            for (int mt = 0; mt < 2; ++mt)
                #pragma unroll
                for (int r = 0; r < 4; ++r) {
                    float vv = (xacc[mt][j][r] + bl) * s + t;
                    vv = (vv >= 0.0f) ? vv : av * vv;
                    yb[(mt * 16 + q * 4 + r) * LDP + cc] = f2bs(vv);
                }
        }
    }
    __syncthreads();   // x visible in yb

    // ---- Phase 2: gi = x @ Wih^T + (bih + bhh[r,z])  (registers) ----
    f32x4 gi[2][3][2] = {};   // [mt][g][j]
    {
        const unsigned short* xa0 = yb + m16 * LDP + q * 8;
        const unsigned short* xa1 = xa0 + 16 * LDP;
        #pragma unroll
        for (int g = 0; g < 3; ++g)
            #pragma unroll
            for (int kk = 0; kk < 8; ++kk) {
                bf16x8 a0 = lds8(xa0 + kk * 32);
                bf16x8 a1 = lds8(xa1 + kk * 32);
                bf16x8 b0 = pk8(WIH_E + (size_t)(((cg * 3 + g) * 8 + kk) * 2 + 0) * 512 + lane8);
                bf16x8 b1 = pk8(WIH_E + (size_t)(((cg * 3 + g) * 8 + kk) * 2 + 1) * 512 + lane8);
                gi[0][g][0] = MFMA16(a0, b0, gi[0][g][0]);
                gi[1][g][0] = MFMA16(a1, b0, gi[1][g][0]);
                gi[0][g][1] = MFMA16(a0, b1, gi[0][g][1]);
                gi[1][g][1] = MFMA16(a1, b1, gi[1][g][1]);
            }
        #pragma unroll
        for (int g = 0; g < 3; ++g)
            #pragma unroll
            for (int j = 0; j < 2; ++j) {
                float bias = ld1<F32>(bih, g * H + cc2[j]);
                if (g < 2) bias += ld1<F32>(bhh, g * H + cc2[j]);
                #pragma unroll
                for (int mt = 0; mt < 2; ++mt)
                    #pragma unroll
                    for (int r = 0; r < 4; ++r) gi[mt][g][j][r] += bias;
            }
    }

    // ---- GRU loop + fused downstream ----
    // Per step t: [gh reads hb(t-1)] [gates] A [write hb,yb] B1
    //             [Wc reads yb -> zb] B2 [Wmu reads zb -> out]
    float hreg[2][2][4] = {};
    const unsigned short* ha0 = hb + m16 * LDP + q * 8;
    const unsigned short* ha1 = ha0 + 16 * LDP;
    const unsigned short* ya0 = yb + m16 * LDP + q * 8;
    const unsigned short* ya1 = ya0 + 16 * LDP;
    const int mto = (cg >> 1) & 1;
    const int nto = cg & 1;
    const unsigned short* zaP = zb + (mto * 16 + m16) * LDP + q * 8;
    const float bmuv = (cg < 4) ? ld1<F32>(bmu, nto * 16 + m16) : 0.0f;

    #pragma unroll 1
    for (int t = 0; t < LSTEPS; ++t) {
        f32x4 gh[2][3][2] = {};
        if (t > 0) {
            #pragma unroll
            for (int g = 0; g < 3; ++g)
                #pragma unroll
                for (int kk = 0; kk < 8; ++kk) {
                    bf16x8 a0 = lds8(ha0 + kk * 32);
                    bf16x8 a1 = lds8(ha1 + kk * 32);
                    bf16x8 b0 = pk8(WHH_E + (size_t)(((cg * 3 + g) * 8 + kk) * 2 + 0) * 512 + lane8);
                    bf16x8 b1 = pk8(WHH_E + (size_t)(((cg * 3 + g) * 8 + kk) * 2 + 1) * 512 + lane8);
                    gh[0][g][0] = MFMA16(a0, b0, gh[0][g][0]);
                    gh[1][g][0] = MFMA16(a1, b0, gh[1][g][0]);
                    gh[0][g][1] = MFMA16(a0, b1, gh[0][g][1]);
                    gh[1][g][1] = MFMA16(a1, b1, gh[1][g][1]);
                }
        }
        // gates + h update + y = prelu(bn2(h))
        float yv[2][2][4];
        #pragma unroll
        for (int mt = 0; mt < 2; ++mt)
            #pragma unroll
            for (int j = 0; j < 2; ++j)
                #pragma unroll
                for (int r = 0; r < 4; ++r) {
                    float rr = sigm(gi[mt][0][j][r] + gh[mt][0][j][r]);
                    float zz = sigm(gi[mt][1][j][r] + gh[mt][1][j][r]);
                    float nin = gi[mt][2][j][r] + rr * (gh[mt][2][j][r] + bhhn[j]);
                    float nn = 2.0f * sigm(2.0f * nin) - 1.0f;   // tanh
                    float hh = (1.0f - zz) * nn + zz * hreg[mt][j][r];
                    hreg[mt][j][r] = hh;
                    float y = hh * s2v[j] + t2v[j];
                    yv[mt][j][r] = (y >= 0.0f) ? y : a2v * y;
                }
        __syncthreads();   // A: all reads of hb/yb/zb from prior phases done
        #pragma unroll
        for (int mt = 0; mt < 2; ++mt)
            #pragma unroll
            for (int j = 0; j < 2; ++j)
                #pragma unroll
                for (int r = 0; r < 4; ++r) {
                    const int idx = (mt * 16 + q * 4 + r) * LDP + cc2[j];
                    hb[idx] = f2bs(hreg[mt][j][r]);
                    yb[idx] = f2bs(yv[mt][j][r]);
                }
        __syncthreads();   // B1: h/y visible

        // w2 = y @ Wc^T -> z -> zb
        f32x4 w2[2][2] = {};
        #pragma unroll
        for (int kk = 0; kk < 8; ++kk) {
            bf16x8 a0 = lds8(ya0 + kk * 32);
            bf16x8 a1 = lds8(ya1 + kk * 32);
            bf16x8 b0 = pk8(WC_E + (size_t)((cg * 8 + kk) * 2 + 0) * 512 + lane8);
            bf16x8 b1 = pk8(WC_E + (size_t)((cg * 8 + kk) * 2 + 1) * 512 + lane8);
            w2[0][0] = MFMA16(a0, b0, w2[0][0]);
            w2[1][0] = MFMA16(a1, b0, w2[1][0]);
            w2[0][1] = MFMA16(a0, b1, w2[0][1]);
            w2[1][1] = MFMA16(a1, b1, w2[1][1]);
        }
        #pragma unroll
        for (int mt = 0; mt < 2; ++mt)
            #pragma unroll
            for (int j = 0; j < 2; ++j)
                #pragma unroll
                for (int r = 0; r < 4; ++r) {
                    float z0 = w2[mt][j][r] * s3v[j] + t3f[j];
                    z0 = (z0 >= 0.0f) ? z0 : a3v * z0;
                    zb[(mt * 16 + q * 4 + r) * LDP + cc2[j]] = f2bs(z0);
                }
        __syncthreads();   // B2: z visible

        // out_t = z @ Wmu^T + bmu   (waves 0..3 own the four 16x16 tiles)
        if (cg < 4) {
            f32x4 o = {};
            #pragma unroll
            for (int kk = 0; kk < 8; ++kk) {
                bf16x8 a = lds8(zaP + kk * 32);
                bf16x8 b = pk8(WMU_E + (size_t)(nto * 8 + kk) * 512 + lane8);
                o = MFMA16(a, b, o);
            }
            #pragma unroll
            for (int r = 0; r < 4; ++r) {
                float vv = o[r] + bmuv;
                const size_t oi = (size_t)(row0 + mto * 16 + q * 4 + r) * (LSTEPS * CO)
                                + t * CO + nto * 16 + m16;
                if constexpr (F32) ((float*)out)[oi] = vv;
                else               ((__hip_bfloat16*)out)[oi] = __float2bfloat16(vv);
            }
        }
        // safe: zb rewritten only after B2(t+1); hb/yb rewritten only after A(t+1)
    }
}

__global__ __launch_bounds__(512, 2) void comm_fast(
    const void* hw, const void* blin,
    const void* g1, const void* be1, const void* m1, const void* v1, const void* a1,
    const void* bih, const void* bhh,
    const void* g2, const void* be2, const void* m2, const void* v2, const void* a2,
    const void* bc,
    const void* g3, const void* be3, const void* m3, const void* v3, const void* a3,
    const void* bmu,
    void* out)
{
    __shared__ __align__(16) unsigned short hb[32 * LDP];
    __shared__ __align__(16) unsigned short yb[32 * LDP];
    __shared__ __align__(16) unsigned short zb[32 * LDP];
    if (g_flag) {
        fast_pipe<true >(hw, blin, g1, be1, m1, v1, a1, bih, bhh,
                         g2, be2, m2, v2, a2, bc, g3, be3, m3, v3, a3, bmu,
                         out, hb, yb, zb);
    } else {
        fast_pipe<false>(hw, blin, g1, be1, m1, v1, a1, bih, bhh,
                         g2, be2, m2, v2, a2, bc, g3, be3, m3, v3, a3, bmu,
                         out, hb, yb, zb);
    }
}

extern "C" void kernel_launch(void* const* d_in, const int* in_sizes, int n_in,
                              void* d_out, int out_size, void* d_ws, size_t ws_size,
                              hipStream_t stream) {
    (void)in_sizes; (void)n_in; (void)out_size; (void)d_ws; (void)ws_size;
    detect_dtype<<<dim3(1), dim3(1), 0, stream>>>(d_in[6]);
    prepack<<<dim3(308), dim3(256), 0, stream>>>(
        d_in[1], d_in[8], d_in[9], d_in[17], d_in[24]);
    comm_fast<<<dim3(256), dim3(512), 0, stream>>>(
        d_in[0], d_in[2],
        d_in[3], d_in[4], d_in[5], d_in[6], d_in[7],
        d_in[10], d_in[11],
        d_in[12], d_in[13], d_in[14], d_in[15], d_in[16],
        d_in[18],
        d_in[19], d_in[20], d_in[21], d_in[22], d_in[23],
        d_in[25],
        d_out);
}